// Round 9
// baseline (1055.292 us; speedup 1.0000x reference)
//
#include <hip/hip_runtime.h>
#include <math.h>

#define HID 64
#define NEG 0.2f
#define BSH 9         // bucket shift: 512 nodes per bucket
#define BNODES 512
#define CH 16384      // edges per chunk
#define NBMAX 256     // max buckets (n <= 131072)

typedef float f32x2 __attribute__((ext_vector_type(2)));

__device__ __forceinline__ unsigned short f2bf(float f) {
    unsigned u = __float_as_uint(f);
    unsigned r = u + 0x7fffu + ((u >> 16) & 1u);   // RNE
    return (unsigned short)(r >> 16);
}

__device__ __forceinline__ f32x2 bf2up(unsigned x) {   // 2 bf16 -> 2 f32
    f32x2 r;
    r.x = __uint_as_float(x << 16);
    r.y = __uint_as_float(x & 0xffff0000u);
    return r;
}

// ---------------- node transform: hbf = bf16(x@W), s = h.a_s, d = h.a_d
template <int CIN>
__global__ void transform_k(const float* __restrict__ xin,
                            const float* __restrict__ W,      // [CIN][64]
                            const float* __restrict__ avs,
                            const float* __restrict__ avd,
                            unsigned short* __restrict__ hbf, // [n][64] bf16
                            float* __restrict__ s_out, float* __restrict__ d_out,
                            int n) {
    __shared__ float Wl[CIN * HID];
    __shared__ float asl[HID], adl[HID];
    for (int i = threadIdx.x; i < CIN * HID; i += blockDim.x) Wl[i] = W[i];
    if (threadIdx.x < HID) { asl[threadIdx.x] = avs[threadIdx.x]; adl[threadIdx.x] = avd[threadIdx.x]; }
    __syncthreads();
    int lane = threadIdx.x & 63;
    int wid = (blockIdx.x * blockDim.x + threadIdx.x) >> 6;
    int nw = (gridDim.x * blockDim.x) >> 6;
    for (int i = wid; i < n; i += nw) {
        float hv = 0.f;
        if (CIN == 1) {
            hv = xin[i] * Wl[lane];
        } else {
            float xv = xin[(size_t)i * CIN + lane];
#pragma unroll
            for (int k = 0; k < CIN; ++k)
                hv += __shfl(xv, k) * Wl[k * HID + lane];
        }
        hbf[(size_t)i * HID + lane] = f2bf(hv);
        float sv = hv * asl[lane], dv = hv * adl[lane];
#pragma unroll
        for (int off = 32; off > 0; off >>= 1) {
            sv += __shfl_xor(sv, off);
            dv += __shfl_xor(dv, off);
        }
        if (lane == 0) { s_out[i] = sv; d_out[i] = dv; }
    }
}

// last layer transform: 64 -> 1 (hL stays fp32, it's only [n])
__global__ void transform_last_k(const float* __restrict__ xin,
                                 const float* __restrict__ WL,
                                 const float* __restrict__ asL, const float* __restrict__ adL,
                                 float* __restrict__ hL,
                                 float* __restrict__ s_out, float* __restrict__ d_out,
                                 int n) {
    __shared__ float Wl[HID];
    if (threadIdx.x < HID) Wl[threadIdx.x] = WL[threadIdx.x];
    __syncthreads();
    float aS = asL[0], aD = adL[0];
    int lane = threadIdx.x & 63;
    int wid = (blockIdx.x * blockDim.x + threadIdx.x) >> 6;
    int nw = (gridDim.x * blockDim.x) >> 6;
    for (int i = wid; i < n; i += nw) {
        float hv = xin[(size_t)i * HID + lane] * Wl[lane];
#pragma unroll
        for (int off = 32; off > 0; off >>= 1) hv += __shfl_xor(hv, off);
        if (lane == 0) {
            hL[i] = hv;
            s_out[i] = hv * aS; d_out[i] = hv * aD;
        }
    }
}

// ---------------- CSR build: deterministic two-pass, ZERO global atomics ----------------
// K1: per-chunk bucket histogram -> counts[c][b]
__global__ __launch_bounds__(256) void chunk_hist_k(const int* __restrict__ ei, int E, int nb,
                                                    int* __restrict__ counts) {
    __shared__ int lh[NBMAX];
    int t = threadIdx.x;
    int base = blockIdx.x * CH;
    int end = base + CH; if (end > E) end = E;
    for (int b = t; b < NBMAX; b += 256) lh[b] = 0;
    __syncthreads();
    for (int e = base + t; e < end; e += 256)
        atomicAdd(&lh[ei[E + e] >> BSH], 1);
    __syncthreads();
    for (int b = t; b < nb; b += 256)
        counts[(size_t)blockIdx.x * nb + b] = lh[b];
}

// K2: per-bucket exclusive prefix over chunks (in place), one wave per bucket; totals out
__global__ void col_scan_k(int* __restrict__ counts, int nchunks, int nb,
                           int* __restrict__ total) {
    int b = (blockIdx.x * blockDim.x + threadIdx.x) >> 6;
    int lane = threadIdx.x & 63;
    if (b >= nb) return;
    int run = 0;
    for (int c0 = 0; c0 < nchunks; c0 += 64) {
        int c = c0 + lane;
        int v = (c < nchunks) ? counts[(size_t)c * nb + b] : 0;
        int inc = v;
#pragma unroll
        for (int o = 1; o < 64; o <<= 1) {
            int w = __shfl_up(inc, o);
            if (lane >= o) inc += w;
        }
        int excl = inc - v + run;
        if (c < nchunks) counts[(size_t)c * nb + b] = excl;
        run += __shfl(inc, 63);
    }
    if (lane == 0) total[b] = run;
}

// K3: scan bucket totals -> pbase
__global__ void bucket_scan_k(const int* __restrict__ total, int* __restrict__ pbase, int nb) {
    __shared__ int s[1024];
    int t = threadIdx.x;
    int v = (t < nb) ? total[t] : 0;
    s[t] = v;
    __syncthreads();
    for (int o = 1; o < 1024; o <<= 1) {
        int x = (t >= o) ? s[t - o] : 0;
        __syncthreads();
        s[t] += x;
        __syncthreads();
    }
    if (t < nb) {
        pbase[t] = s[t] - v;
        if (t == nb - 1) pbase[nb] = s[t];
    }
}

// K4: scatter; LDS cursors seeded from deterministic bases — no global atomics
__global__ __launch_bounds__(256) void chunk_scatter_k(const int* __restrict__ ei, int E, int nb,
                                                       const int* __restrict__ counts,
                                                       const int* __restrict__ pbase,
                                                       unsigned* __restrict__ pairs) {
    __shared__ int lcur[NBMAX];
    int t = threadIdx.x;
    int c = blockIdx.x;
    int base = c * CH;
    int end = base + CH; if (end > E) end = E;
    for (int b = t; b < nb; b += 256)
        lcur[b] = pbase[b] + counts[(size_t)c * nb + b];
    __syncthreads();
    for (int e = base + t; e < end; e += 256) {
        int u = ei[e], v = ei[E + e];
        int b = v >> BSH;
        int pos = atomicAdd(&lcur[b], 1);
        pairs[pos] = ((unsigned)u << BSH) | (unsigned)(v & (BNODES - 1));
    }
}

// K5: one block (512 thr) per bucket; LDS counting sort over 512 nodes; writes off[] and csr
__global__ __launch_bounds__(512) void csr_build_k(const unsigned* __restrict__ pairs,
                                                   const int* __restrict__ pbase,
                                                   int nb, int n,
                                                   int* __restrict__ off, int* __restrict__ csr) {
    __shared__ int cnt[BNODES];
    __shared__ int sc[BNODES];
    __shared__ int cur[BNODES];
    int b = blockIdx.x;
    int pb = pbase[b], pe = pbase[b + 1];
    int node0 = b << BSH;
    int nnode = n - node0; if (nnode > BNODES) nnode = BNODES;
    int cbase = pb + node0;
    int t = threadIdx.x;
    cnt[t] = 0;
    __syncthreads();
    for (int i = pb + t; i < pe; i += blockDim.x)
        atomicAdd(&cnt[pairs[i] & (BNODES - 1)], 1);
    __syncthreads();
    int deg = (t < nnode) ? cnt[t] + 1 : 0;   // +1 self loop
    sc[t] = deg;
    __syncthreads();
#pragma unroll
    for (int o = 1; o < BNODES; o <<= 1) {
        int x = (t >= o) ? sc[t - o] : 0;
        __syncthreads();
        sc[t] += x;
        __syncthreads();
    }
    if (t < nnode) {
        int excl = sc[t] - deg;
        off[node0 + t] = cbase + excl;
        cur[t] = excl;
        csr[cbase + excl + cnt[t]] = node0 + t;    // self-loop slot
    }
    if (b == nb - 1 && t == 0) off[n] = cbase + sc[BNODES - 1];
    __syncthreads();
    for (int i = pb + t; i < pe; i += blockDim.x) {
        unsigned p = pairs[i];
        int j = p & (BNODES - 1);
        int pos = atomicAdd(&cur[j], 1);
        csr[cbase + pos] = (int)(p >> BSH);
    }
}

// ---------------- fused softmax+aggregate: single phase, no max pass.
// Softmax is shift-invariant; logits bounded (|t| ~< 10) so exp() cannot overflow.
// 64-edge blocks: each lane computes exp for ITS edge once (no 8x replication),
// exchanges {e,u} via wave-local LDS (R4-proven pattern), then 8 lanes/edge do
// the channel FMAs with uint4 loads + packed f32 FMA.
__global__ __launch_bounds__(256) void gat_agg_k(
    const int* __restrict__ off, const int* __restrict__ csr,
    const float* __restrict__ s, const float* __restrict__ d,
    const unsigned short* __restrict__ hbf, const float* __restrict__ b,
    float* __restrict__ out, int n) {
    __shared__ uint2 eu_lds[4][64];
    int lane = threadIdx.x & 63;
    int wsub = threadIdx.x >> 6;
    int sub = lane & 7;         // channel group: channels sub*8 .. sub*8+7
    int q = lane >> 3;          // edge slot 0..7
    int ch = sub * 8;
    int wid = (blockIdx.x * blockDim.x + threadIdx.x) >> 6;
    int nw = (gridDim.x * blockDim.x) >> 6;
    float4 bb0 = *(const float4*)&b[ch];
    float4 bb1 = *(const float4*)&b[ch + 4];
    for (int v = wid; v < n; v += nw) {
        int beg = off[v];
        int deg = off[v + 1] - beg;
        float dv = d[v];
        float l = 0.f;
        f32x2 a01 = {0.f, 0.f}, a23 = {0.f, 0.f}, a45 = {0.f, 0.f}, a67 = {0.f, 0.f};
        for (int base = 0; base < deg; base += 64) {
            int rem = deg - base;
            int kmax = rem < 64 ? rem : 64;
            // phase 1: this lane's own edge — exp computed exactly once per edge
            float e = 0.f; unsigned u = 0u;
            if (lane < kmax) {
                u = (unsigned)csr[beg + base + lane];
                float t = s[u] + dv;
                t = t > 0.f ? t : NEG * t;
                e = __expf(t);
            }
            l += e;
            eu_lds[wsub][lane] = make_uint2(__float_as_uint(e), u);
            // phase 2: channel FMAs; lane covers edges k ≡ q (mod 8) of this block
            for (int k = q; k < kmax; k += 8) {
                uint2 eu = eu_lds[wsub][k];          // ds_read_b64 broadcast
                float ek = __uint_as_float(eu.x);
                unsigned uk = eu.y;
                uint4 hv = *(const uint4*)&hbf[(size_t)uk * HID + ch];
                f32x2 e2; e2.x = ek; e2.y = ek;
                a01 += e2 * bf2up(hv.x);
                a23 += e2 * bf2up(hv.y);
                a45 += e2 * bf2up(hv.z);
                a67 += e2 * bf2up(hv.w);
            }
        }
        // reduce: acc over the 8 edge slots (q); l over all 64 lanes
#pragma unroll
        for (int o = 8; o < 64; o <<= 1) {
            a01.x += __shfl_xor(a01.x, o); a01.y += __shfl_xor(a01.y, o);
            a23.x += __shfl_xor(a23.x, o); a23.y += __shfl_xor(a23.y, o);
            a45.x += __shfl_xor(a45.x, o); a45.y += __shfl_xor(a45.y, o);
            a67.x += __shfl_xor(a67.x, o); a67.y += __shfl_xor(a67.y, o);
        }
#pragma unroll
        for (int o = 1; o < 64; o <<= 1) l += __shfl_xor(l, o);
        if (q == 0) {
            float inv = 1.f / l;
            float4 r0, r1;
            r0.x = a01.x * inv + bb0.x; r0.y = a01.y * inv + bb0.y;
            r0.z = a23.x * inv + bb0.z; r0.w = a23.y * inv + bb0.w;
            r1.x = a45.x * inv + bb1.x; r1.y = a45.y * inv + bb1.y;
            r1.z = a67.x * inv + bb1.z; r1.w = a67.y * inv + bb1.w;
            r0.x = r0.x > 0.f ? r0.x : 0.f; r0.y = r0.y > 0.f ? r0.y : 0.f;
            r0.z = r0.z > 0.f ? r0.z : 0.f; r0.w = r0.w > 0.f ? r0.w : 0.f;
            r1.x = r1.x > 0.f ? r1.x : 0.f; r1.y = r1.y > 0.f ? r1.y : 0.f;
            r1.z = r1.z > 0.f ? r1.z : 0.f; r1.w = r1.w > 0.f ? r1.w : 0.f;
            *(float4*)&out[(size_t)v * HID + ch] = r0;
            *(float4*)&out[(size_t)v * HID + ch + 4] = r1;
        }
    }
}

// last layer aggregate (1 channel): single pass, 4-way unroll for MLP
__global__ void gat_agg1_k(const int* __restrict__ off, const int* __restrict__ csr,
                           const float* __restrict__ s, const float* __restrict__ d,
                           const float* __restrict__ hL, const float* __restrict__ bL,
                           float* __restrict__ out, int n) {
    int lane = threadIdx.x & 63;
    int wid = (blockIdx.x * blockDim.x + threadIdx.x) >> 6;
    int nw = (gridDim.x * blockDim.x) >> 6;
    float bias = bL[0];
    for (int v = wid; v < n; v += nw) {
        int beg = off[v], end = off[v + 1];
        float dv = d[v];
        float l = 0.f, acc = 0.f;
        int i = beg + lane;
        for (; i + 192 < end; i += 256) {   // 4 edges in flight per lane
            int u0 = csr[i], u1 = csr[i + 64], u2 = csr[i + 128], u3 = csr[i + 192];
            float t0 = s[u0] + dv, t1 = s[u1] + dv, t2 = s[u2] + dv, t3 = s[u3] + dv;
            float h0 = hL[u0], h1 = hL[u1], h2 = hL[u2], h3 = hL[u3];
            t0 = t0 > 0.f ? t0 : NEG * t0; t1 = t1 > 0.f ? t1 : NEG * t1;
            t2 = t2 > 0.f ? t2 : NEG * t2; t3 = t3 > 0.f ? t3 : NEG * t3;
            float e0 = __expf(t0), e1 = __expf(t1), e2 = __expf(t2), e3 = __expf(t3);
            l += e0 + e1 + e2 + e3;
            acc += e0 * h0 + e1 * h1 + e2 * h2 + e3 * h3;
        }
        for (; i < end; i += 64) {
            int u = csr[i];
            float t = s[u] + dv;
            t = t > 0.f ? t : NEG * t;
            float e = __expf(t);
            l += e;
            acc += e * hL[u];
        }
#pragma unroll
        for (int o = 32; o > 0; o >>= 1) {
            l += __shfl_xor(l, o);
            acc += __shfl_xor(acc, o);
        }
        if (lane == 0) {
            float r = acc / l + bias;
            out[v] = 1.f / (1.f + __expf(-r));  // sigmoid
        }
    }
}

extern "C" void kernel_launch(void* const* d_in, const int* in_sizes, int n_in,
                              void* d_out, int out_size, void* d_ws, size_t ws_size,
                              hipStream_t stream) {
    const float* x   = (const float*)d_in[0];
    const int*   ei  = (const int*)d_in[1];
    // d_in[2] = edge_weight: ignored (edge_dim=None)
    const float* W0  = (const float*)d_in[3];
    const float* as0 = (const float*)d_in[4];
    const float* ad0 = (const float*)d_in[5];
    const float* b0  = (const float*)d_in[6];
    const float* Wm  = (const float*)d_in[7];
    const float* asm_ = (const float*)d_in[8];
    const float* adm = (const float*)d_in[9];
    const float* bm  = (const float*)d_in[10];
    const float* WL  = (const float*)d_in[11];
    const float* asL = (const float*)d_in[12];
    const float* adL = (const float*)d_in[13];
    const float* bL  = (const float*)d_in[14];

    const int n = in_sizes[0];      // 100000
    const int E = in_sizes[1] / 2;  // 6400000
    const int nb = (n + BNODES - 1) >> BSH;  // 196 buckets
    const int gChunk = (E + CH - 1) / CH;    // 391 chunks

    // workspace: h[n*64]f (hbf/hL alias; counts[] aliases during CSR build) |
    //            A[n*64]f (pairs[] aliases during CSR build) |
    //            s[n] | d[n] | off[n+1] | csr[E+n] | total[nb] | pbase[nb+1]
    float* ws   = (float*)d_ws;
    float* h    = ws;
    unsigned short* hbf = (unsigned short*)ws;
    float* A    = ws + (size_t)n * HID;
    float* sbuf = ws + 2 * (size_t)n * HID;
    float* dbuf = sbuf + n;
    int* off    = (int*)(dbuf + n);
    int* csr    = off + n + 1;
    int* total  = csr + E + n;
    int* pbase  = total + nb;
    int* counts = (int*)h;            // gChunk*nb ints << 25.6 MB; pre-transform only
    unsigned* pairs = (unsigned*)A;   // E ints; pre-agg only

    const int BLK = 256;
    const int gTrans = 2048;
    const int gAgg   = (n + 3) / 4;   // 1 node per wave

    // ---- CSR build (deterministic bases; zero global atomics)
    chunk_hist_k<<<gChunk, BLK, 0, stream>>>(ei, E, nb, counts);
    col_scan_k<<<(nb + 3) / 4, BLK, 0, stream>>>(counts, gChunk, nb, total);
    bucket_scan_k<<<1, 1024, 0, stream>>>(total, pbase, nb);
    chunk_scatter_k<<<gChunk, BLK, 0, stream>>>(ei, E, nb, counts, pbase, pairs);
    csr_build_k<<<nb, 512, 0, stream>>>(pairs, pbase, nb, n, off, csr);

    // ---- layer 0: 1 -> 64, ReLU
    transform_k<1><<<gTrans, BLK, 0, stream>>>(x, W0, as0, ad0, hbf, sbuf, dbuf, n);
    gat_agg_k<<<gAgg, BLK, 0, stream>>>(off, csr, sbuf, dbuf, hbf, b0, A, n);

    // ---- middle layers: 64 -> 64, ReLU
    for (int l = 0; l < 3; ++l) {
        transform_k<64><<<gTrans, BLK, 0, stream>>>(A, Wm + (size_t)l * HID * HID,
                                                    asm_ + l * HID, adm + l * HID,
                                                    hbf, sbuf, dbuf, n);
        gat_agg_k<<<gAgg, BLK, 0, stream>>>(off, csr, sbuf, dbuf, hbf, bm + l * HID, A, n);
    }

    // ---- last layer: 64 -> 1, sigmoid (hL aliases h region as fp32)
    transform_last_k<<<gTrans, BLK, 0, stream>>>(A, WL, asL, adL, h, sbuf, dbuf, n);
    gat_agg1_k<<<gAgg, BLK, 0, stream>>>(off, csr, sbuf, dbuf, h, bL, (float*)d_out, n);
}

// Round 10
// 997.939 us; speedup vs baseline: 1.0575x; 1.0575x over previous
//
#include <hip/hip_runtime.h>
#include <math.h>

#define HID 64
#define NEG 0.2f
#define BSH 9         // bucket shift: 512 nodes per bucket
#define BNODES 512
#define CH 16384      // edges per chunk
#define NBMAX 256     // max buckets (n <= 131072)

typedef float f32x2 __attribute__((ext_vector_type(2)));

// ---------------- node transform: hf8 = fp8_e4m3(x@W), s = h.a_s, d = h.a_d
template <int CIN>
__global__ void transform_k(const float* __restrict__ xin,
                            const float* __restrict__ W,      // [CIN][64]
                            const float* __restrict__ avs,
                            const float* __restrict__ avd,
                            unsigned char* __restrict__ hf8,  // [n][64] fp8 e4m3
                            float* __restrict__ s_out, float* __restrict__ d_out,
                            int n) {
    __shared__ float Wl[CIN * HID];
    __shared__ float asl[HID], adl[HID];
    for (int i = threadIdx.x; i < CIN * HID; i += blockDim.x) Wl[i] = W[i];
    if (threadIdx.x < HID) { asl[threadIdx.x] = avs[threadIdx.x]; adl[threadIdx.x] = avd[threadIdx.x]; }
    __syncthreads();
    int lane = threadIdx.x & 63;
    int wid = (blockIdx.x * blockDim.x + threadIdx.x) >> 6;
    int nw = (gridDim.x * blockDim.x) >> 6;
    for (int i = wid; i < n; i += nw) {
        float hv = 0.f;
        if (CIN == 1) {
            hv = xin[i] * Wl[lane];
        } else {
            float xv = xin[(size_t)i * CIN + lane];
#pragma unroll
            for (int k = 0; k < CIN; ++k)
                hv += __shfl(xv, k) * Wl[k * HID + lane];
        }
        int pk = __builtin_amdgcn_cvt_pk_fp8_f32(hv, hv, 0, false);  // HW RNE cvt
        hf8[(size_t)i * HID + lane] = (unsigned char)(pk & 0xff);
        float sv = hv * asl[lane], dv = hv * adl[lane];
#pragma unroll
        for (int off = 32; off > 0; off >>= 1) {
            sv += __shfl_xor(sv, off);
            dv += __shfl_xor(dv, off);
        }
        if (lane == 0) { s_out[i] = sv; d_out[i] = dv; }
    }
}

// last layer transform: 64 -> 1; packs {s, hL} as float2 so agg1 does 1 gather/edge
__global__ void transform_last_k(const float* __restrict__ xin,
                                 const float* __restrict__ WL,
                                 const float* __restrict__ asL, const float* __restrict__ adL,
                                 float2* __restrict__ sh2,     // [n] {s_u, hL_u}
                                 float* __restrict__ d_out,
                                 int n) {
    __shared__ float Wl[HID];
    if (threadIdx.x < HID) Wl[threadIdx.x] = WL[threadIdx.x];
    __syncthreads();
    float aS = asL[0], aD = adL[0];
    int lane = threadIdx.x & 63;
    int wid = (blockIdx.x * blockDim.x + threadIdx.x) >> 6;
    int nw = (gridDim.x * blockDim.x) >> 6;
    for (int i = wid; i < n; i += nw) {
        float hv = xin[(size_t)i * HID + lane] * Wl[lane];
#pragma unroll
        for (int off = 32; off > 0; off >>= 1) hv += __shfl_xor(hv, off);
        if (lane == 0) {
            sh2[i] = make_float2(hv * aS, hv);
            d_out[i] = hv * aD;
        }
    }
}

// ---------------- CSR build: deterministic two-pass, ZERO global atomics ----------------
__global__ __launch_bounds__(256) void chunk_hist_k(const int* __restrict__ ei, int E, int nb,
                                                    int* __restrict__ counts) {
    __shared__ int lh[NBMAX];
    int t = threadIdx.x;
    int base = blockIdx.x * CH;
    int end = base + CH; if (end > E) end = E;
    for (int b = t; b < NBMAX; b += 256) lh[b] = 0;
    __syncthreads();
    for (int e = base + t; e < end; e += 256)
        atomicAdd(&lh[ei[E + e] >> BSH], 1);
    __syncthreads();
    for (int b = t; b < nb; b += 256)
        counts[(size_t)blockIdx.x * nb + b] = lh[b];
}

__global__ void col_scan_k(int* __restrict__ counts, int nchunks, int nb,
                           int* __restrict__ total) {
    int b = (blockIdx.x * blockDim.x + threadIdx.x) >> 6;
    int lane = threadIdx.x & 63;
    if (b >= nb) return;
    int run = 0;
    for (int c0 = 0; c0 < nchunks; c0 += 64) {
        int c = c0 + lane;
        int v = (c < nchunks) ? counts[(size_t)c * nb + b] : 0;
        int inc = v;
#pragma unroll
        for (int o = 1; o < 64; o <<= 1) {
            int w = __shfl_up(inc, o);
            if (lane >= o) inc += w;
        }
        int excl = inc - v + run;
        if (c < nchunks) counts[(size_t)c * nb + b] = excl;
        run += __shfl(inc, 63);
    }
    if (lane == 0) total[b] = run;
}

__global__ void bucket_scan_k(const int* __restrict__ total, int* __restrict__ pbase, int nb) {
    __shared__ int s[1024];
    int t = threadIdx.x;
    int v = (t < nb) ? total[t] : 0;
    s[t] = v;
    __syncthreads();
    for (int o = 1; o < 1024; o <<= 1) {
        int x = (t >= o) ? s[t - o] : 0;
        __syncthreads();
        s[t] += x;
        __syncthreads();
    }
    if (t < nb) {
        pbase[t] = s[t] - v;
        if (t == nb - 1) pbase[nb] = s[t];
    }
}

__global__ __launch_bounds__(256) void chunk_scatter_k(const int* __restrict__ ei, int E, int nb,
                                                       const int* __restrict__ counts,
                                                       const int* __restrict__ pbase,
                                                       unsigned* __restrict__ pairs) {
    __shared__ int lcur[NBMAX];
    int t = threadIdx.x;
    int c = blockIdx.x;
    int base = c * CH;
    int end = base + CH; if (end > E) end = E;
    for (int b = t; b < nb; b += 256)
        lcur[b] = pbase[b] + counts[(size_t)c * nb + b];
    __syncthreads();
    for (int e = base + t; e < end; e += 256) {
        int u = ei[e], v = ei[E + e];
        int b = v >> BSH;
        int pos = atomicAdd(&lcur[b], 1);
        pairs[pos] = ((unsigned)u << BSH) | (unsigned)(v & (BNODES - 1));
    }
}

__global__ __launch_bounds__(512) void csr_build_k(const unsigned* __restrict__ pairs,
                                                   const int* __restrict__ pbase,
                                                   int nb, int n,
                                                   int* __restrict__ off, int* __restrict__ csr) {
    __shared__ int cnt[BNODES];
    __shared__ int sc[BNODES];
    __shared__ int cur[BNODES];
    int b = blockIdx.x;
    int pb = pbase[b], pe = pbase[b + 1];
    int node0 = b << BSH;
    int nnode = n - node0; if (nnode > BNODES) nnode = BNODES;
    int cbase = pb + node0;
    int t = threadIdx.x;
    cnt[t] = 0;
    __syncthreads();
    for (int i = pb + t; i < pe; i += blockDim.x)
        atomicAdd(&cnt[pairs[i] & (BNODES - 1)], 1);
    __syncthreads();
    int deg = (t < nnode) ? cnt[t] + 1 : 0;   // +1 self loop
    sc[t] = deg;
    __syncthreads();
#pragma unroll
    for (int o = 1; o < BNODES; o <<= 1) {
        int x = (t >= o) ? sc[t - o] : 0;
        __syncthreads();
        sc[t] += x;
        __syncthreads();
    }
    if (t < nnode) {
        int excl = sc[t] - deg;
        off[node0 + t] = cbase + excl;
        cur[t] = excl;
        csr[cbase + excl + cnt[t]] = node0 + t;    // self-loop slot
    }
    if (b == nb - 1 && t == 0) off[n] = cbase + sc[BNODES - 1];
    __syncthreads();
    for (int i = pb + t; i < pe; i += blockDim.x) {
        unsigned p = pairs[i];
        int j = p & (BNODES - 1);
        int pos = atomicAdd(&cur[j], 1);
        csr[cbase + pos] = (int)(p >> BSH);
    }
}

// ---------------- fused softmax+aggregate: single phase, no max pass.
// Softmax is shift-invariant; logits bounded so exp() cannot overflow.
// Lane owns one edge for exp (computed once), exchanges {e,u} via wave-local LDS;
// 8 lanes/edge for channel FMAs. h row is fp8 e4m3 = 64 B = ONE cache line;
// uint2 load (8 fp8) per lane, HW cvt_pk_f32_fp8 unpack, packed f32 FMA.
__global__ __launch_bounds__(256) void gat_agg_k(
    const int* __restrict__ off, const int* __restrict__ csr,
    const float* __restrict__ s, const float* __restrict__ d,
    const unsigned char* __restrict__ hf8, const float* __restrict__ b,
    float* __restrict__ out, int n) {
    __shared__ uint2 eu_lds[4][64];
    int lane = threadIdx.x & 63;
    int wsub = threadIdx.x >> 6;
    int sub = lane & 7;         // channel group: channels sub*8 .. sub*8+7
    int q = lane >> 3;          // edge slot 0..7
    int ch = sub * 8;
    int wid = (blockIdx.x * blockDim.x + threadIdx.x) >> 6;
    int nw = (gridDim.x * blockDim.x) >> 6;
    float4 bb0 = *(const float4*)&b[ch];
    float4 bb1 = *(const float4*)&b[ch + 4];
    for (int v = wid; v < n; v += nw) {
        int beg = off[v];
        int deg = off[v + 1] - beg;
        float dv = d[v];
        float l = 0.f;
        f32x2 a01 = {0.f, 0.f}, a23 = {0.f, 0.f}, a45 = {0.f, 0.f}, a67 = {0.f, 0.f};
        for (int base = 0; base < deg; base += 64) {
            int rem = deg - base;
            int kmax = rem < 64 ? rem : 64;
            // phase 1: this lane's own edge — exp computed exactly once per edge
            float e = 0.f; unsigned u = 0u;
            if (lane < kmax) {
                u = (unsigned)csr[beg + base + lane];
                float t = s[u] + dv;
                t = t > 0.f ? t : NEG * t;
                e = __expf(t);
            }
            l += e;
            eu_lds[wsub][lane] = make_uint2(__float_as_uint(e), u);
            // phase 2: channel FMAs; lane covers edges k ≡ q (mod 8) of this block
            for (int k = q; k < kmax; k += 8) {
                uint2 eu = eu_lds[wsub][k];          // ds_read_b64 broadcast
                float ek = __uint_as_float(eu.x);
                unsigned uk = eu.y;
                uint2 hv = *(const uint2*)&hf8[(size_t)uk * HID + ch];  // 8 fp8
                f32x2 e2; e2.x = ek; e2.y = ek;
                a01 += e2 * (f32x2)__builtin_amdgcn_cvt_pk_f32_fp8(hv.x, false);
                a23 += e2 * (f32x2)__builtin_amdgcn_cvt_pk_f32_fp8(hv.x, true);
                a45 += e2 * (f32x2)__builtin_amdgcn_cvt_pk_f32_fp8(hv.y, false);
                a67 += e2 * (f32x2)__builtin_amdgcn_cvt_pk_f32_fp8(hv.y, true);
            }
        }
        // reduce: acc over the 8 edge slots (q); l over all 64 lanes
#pragma unroll
        for (int o = 8; o < 64; o <<= 1) {
            a01.x += __shfl_xor(a01.x, o); a01.y += __shfl_xor(a01.y, o);
            a23.x += __shfl_xor(a23.x, o); a23.y += __shfl_xor(a23.y, o);
            a45.x += __shfl_xor(a45.x, o); a45.y += __shfl_xor(a45.y, o);
            a67.x += __shfl_xor(a67.x, o); a67.y += __shfl_xor(a67.y, o);
        }
#pragma unroll
        for (int o = 1; o < 64; o <<= 1) l += __shfl_xor(l, o);
        if (q == 0) {
            float inv = 1.f / l;
            float4 r0, r1;
            r0.x = a01.x * inv + bb0.x; r0.y = a01.y * inv + bb0.y;
            r0.z = a23.x * inv + bb0.z; r0.w = a23.y * inv + bb0.w;
            r1.x = a45.x * inv + bb1.x; r1.y = a45.y * inv + bb1.y;
            r1.z = a67.x * inv + bb1.z; r1.w = a67.y * inv + bb1.w;
            r0.x = r0.x > 0.f ? r0.x : 0.f; r0.y = r0.y > 0.f ? r0.y : 0.f;
            r0.z = r0.z > 0.f ? r0.z : 0.f; r0.w = r0.w > 0.f ? r0.w : 0.f;
            r1.x = r1.x > 0.f ? r1.x : 0.f; r1.y = r1.y > 0.f ? r1.y : 0.f;
            r1.z = r1.z > 0.f ? r1.z : 0.f; r1.w = r1.w > 0.f ? r1.w : 0.f;
            *(float4*)&out[(size_t)v * HID + ch] = r0;
            *(float4*)&out[(size_t)v * HID + ch + 4] = r1;
        }
    }
}

// last layer aggregate (1 channel): single gather/edge ({s,hL} packed), 4-way unroll
__global__ void gat_agg1_k(const int* __restrict__ off, const int* __restrict__ csr,
                           const float2* __restrict__ sh2, const float* __restrict__ d,
                           const float* __restrict__ bL,
                           float* __restrict__ out, int n) {
    int lane = threadIdx.x & 63;
    int wid = (blockIdx.x * blockDim.x + threadIdx.x) >> 6;
    int nw = (gridDim.x * blockDim.x) >> 6;
    float bias = bL[0];
    for (int v = wid; v < n; v += nw) {
        int beg = off[v], end = off[v + 1];
        float dv = d[v];
        float l = 0.f, acc = 0.f;
        int i = beg + lane;
        for (; i + 192 < end; i += 256) {   // 4 edges in flight per lane
            int u0 = csr[i], u1 = csr[i + 64], u2 = csr[i + 128], u3 = csr[i + 192];
            float2 p0 = sh2[u0], p1 = sh2[u1], p2 = sh2[u2], p3 = sh2[u3];
            float t0 = p0.x + dv, t1 = p1.x + dv, t2 = p2.x + dv, t3 = p3.x + dv;
            t0 = t0 > 0.f ? t0 : NEG * t0; t1 = t1 > 0.f ? t1 : NEG * t1;
            t2 = t2 > 0.f ? t2 : NEG * t2; t3 = t3 > 0.f ? t3 : NEG * t3;
            float e0 = __expf(t0), e1 = __expf(t1), e2 = __expf(t2), e3 = __expf(t3);
            l += e0 + e1 + e2 + e3;
            acc += e0 * p0.y + e1 * p1.y + e2 * p2.y + e3 * p3.y;
        }
        for (; i < end; i += 64) {
            int u = csr[i];
            float2 p = sh2[u];
            float t = p.x + dv;
            t = t > 0.f ? t : NEG * t;
            float e = __expf(t);
            l += e;
            acc += e * p.y;
        }
#pragma unroll
        for (int o = 32; o > 0; o >>= 1) {
            l += __shfl_xor(l, o);
            acc += __shfl_xor(acc, o);
        }
        if (lane == 0) {
            float r = acc / l + bias;
            out[v] = 1.f / (1.f + __expf(-r));  // sigmoid
        }
    }
}

extern "C" void kernel_launch(void* const* d_in, const int* in_sizes, int n_in,
                              void* d_out, int out_size, void* d_ws, size_t ws_size,
                              hipStream_t stream) {
    const float* x   = (const float*)d_in[0];
    const int*   ei  = (const int*)d_in[1];
    // d_in[2] = edge_weight: ignored (edge_dim=None)
    const float* W0  = (const float*)d_in[3];
    const float* as0 = (const float*)d_in[4];
    const float* ad0 = (const float*)d_in[5];
    const float* b0  = (const float*)d_in[6];
    const float* Wm  = (const float*)d_in[7];
    const float* asm_ = (const float*)d_in[8];
    const float* adm = (const float*)d_in[9];
    const float* bm  = (const float*)d_in[10];
    const float* WL  = (const float*)d_in[11];
    const float* asL = (const float*)d_in[12];
    const float* adL = (const float*)d_in[13];
    const float* bL  = (const float*)d_in[14];

    const int n = in_sizes[0];      // 100000
    const int E = in_sizes[1] / 2;  // 6400000
    const int nb = (n + BNODES - 1) >> BSH;  // 196 buckets
    const int gChunk = (E + CH - 1) / CH;    // 391 chunks

    // workspace: h[n*64]f (hf8/sh2 alias; counts[] aliases during CSR build) |
    //            A[n*64]f (pairs[] aliases during CSR build) |
    //            s[n] | d[n] | off[n+1] | csr[E+n] | total[nb] | pbase[nb+1]
    float* ws   = (float*)d_ws;
    float* h    = ws;
    unsigned char* hf8 = (unsigned char*)ws;
    float2* sh2 = (float2*)ws;
    float* A    = ws + (size_t)n * HID;
    float* sbuf = ws + 2 * (size_t)n * HID;
    float* dbuf = sbuf + n;
    int* off    = (int*)(dbuf + n);
    int* csr    = off + n + 1;
    int* total  = csr + E + n;
    int* pbase  = total + nb;
    int* counts = (int*)h;            // gChunk*nb ints << region; pre-transform only
    unsigned* pairs = (unsigned*)A;   // E ints; pre-agg only

    const int BLK = 256;
    const int gTrans = 2048;
    const int gAgg   = (n + 3) / 4;   // 1 node per wave

    // ---- CSR build (deterministic bases; zero global atomics)
    chunk_hist_k<<<gChunk, BLK, 0, stream>>>(ei, E, nb, counts);
    col_scan_k<<<(nb + 3) / 4, BLK, 0, stream>>>(counts, gChunk, nb, total);
    bucket_scan_k<<<1, 1024, 0, stream>>>(total, pbase, nb);
    chunk_scatter_k<<<gChunk, BLK, 0, stream>>>(ei, E, nb, counts, pbase, pairs);
    csr_build_k<<<nb, 512, 0, stream>>>(pairs, pbase, nb, n, off, csr);

    // ---- layer 0: 1 -> 64, ReLU
    transform_k<1><<<gTrans, BLK, 0, stream>>>(x, W0, as0, ad0, hf8, sbuf, dbuf, n);
    gat_agg_k<<<gAgg, BLK, 0, stream>>>(off, csr, sbuf, dbuf, hf8, b0, A, n);

    // ---- middle layers: 64 -> 64, ReLU
    for (int l = 0; l < 3; ++l) {
        transform_k<64><<<gTrans, BLK, 0, stream>>>(A, Wm + (size_t)l * HID * HID,
                                                    asm_ + l * HID, adm + l * HID,
                                                    hf8, sbuf, dbuf, n);
        gat_agg_k<<<gAgg, BLK, 0, stream>>>(off, csr, sbuf, dbuf, hf8, bm + l * HID, A, n);
    }

    // ---- last layer: 64 -> 1, sigmoid ({s,hL} packed into sh2, aliasing h region)
    transform_last_k<<<gTrans, BLK, 0, stream>>>(A, WL, asL, adL, sh2, dbuf, n);
    gat_agg1_k<<<gAgg, BLK, 0, stream>>>(off, csr, sh2, dbuf, bL, (float*)d_out, n);
}